// Round 5
// baseline (2693.156 us; speedup 1.0000x reference)
//
#include <hip/hip_runtime.h>
#include <cstdint>
#include <cstddef>

#define T_STEPS 1000
#define NS      512
#define HID     128
#define DOUT    20
#define XPAD    129   // x tile row pad (dense kernel)
#define PSTR    130   // paired-LDS row stride in dwords (128 pairs + 2 pad)
#define SPMM_R  32    // rows per wave in spmm

// ---------------------------------------------------------------------------
// P0: dense precompute D[row][o] = dot(x_row, Wi1[o][:]). Bit-exact 4-acc
// stride-4 fmaf chain (verified absmax=0.0 rounds 1-4). DO NOT reorder.
// ---------------------------------------------------------------------------
extern "C" __global__ void __launch_bounds__(512, 1)
srnn_dense(const float* __restrict__ x, const float* __restrict__ Wi1,
           float* __restrict__ D, int t0, int Tc)
{
    extern __shared__ float sm[];
    float* xs = sm;                    // [128 rows][XPAD]
    float* Wl = sm + 128 * XPAD;       // Wi1 row-major [128][128]
    const int tid = threadIdx.x;
    const int w = tid >> 6, ln = tid & 63;
    const int rb = blockIdx.x * 128;

    for (int i = tid; i < HID * HID / 4; i += 512)
        ((float4*)Wl)[i] = ((const float4*)Wi1)[i];
    for (int i = tid; i < 128 * 32; i += 512) {
        int r = i >> 5, kq = i & 31;
        int cr = rb + r;
        int s = cr / Tc, trel = cr - s * Tc;
        float4 v = ((const float4*)x)[((size_t)s * T_STEPS + t0 + trel) * 32 + kq];
        float* dst = &xs[r * XPAD + 4 * kq];
        dst[0] = v.x; dst[1] = v.y; dst[2] = v.z; dst[3] = v.w;
    }
    __syncthreads();

    const float* xr0 = xs + ln * XPAD;
    const float* xr1 = xs + (64 + ln) * XPAD;
    for (int og = 0; og < 4; ++og) {
        const int o = 16 * w + 4 * og;
        float a[2][4][4];
        #pragma unroll
        for (int r = 0; r < 2; ++r)
            #pragma unroll
            for (int j = 0; j < 4; ++j)
                #pragma unroll
                for (int i = 0; i < 4; ++i) a[r][j][i] = 0.f;

        #pragma unroll 4
        for (int k = 0; k < HID; k += 4) {
            float4 wv[4];
            #pragma unroll
            for (int j = 0; j < 4; ++j)
                wv[j] = *(const float4*)&Wl[(o + j) * HID + k];
            float xa0[4], xa1[4];
            #pragma unroll
            for (int i = 0; i < 4; ++i) { xa0[i] = xr0[k + i]; xa1[i] = xr1[k + i]; }
            #pragma unroll
            for (int j = 0; j < 4; ++j) {
                a[0][j][0] = fmaf(xa0[0], wv[j].x, a[0][j][0]);
                a[0][j][1] = fmaf(xa0[1], wv[j].y, a[0][j][1]);
                a[0][j][2] = fmaf(xa0[2], wv[j].z, a[0][j][2]);
                a[0][j][3] = fmaf(xa0[3], wv[j].w, a[0][j][3]);
                a[1][j][0] = fmaf(xa1[0], wv[j].x, a[1][j][0]);
                a[1][j][1] = fmaf(xa1[1], wv[j].y, a[1][j][1]);
                a[1][j][2] = fmaf(xa1[2], wv[j].z, a[1][j][2]);
                a[1][j][3] = fmaf(xa1[3], wv[j].w, a[1][j][3]);
            }
        }
        #pragma unroll
        for (int r = 0; r < 2; ++r) {
            float4 dv;
            dv.x = (a[r][0][0] + a[r][0][1]) + (a[r][0][2] + a[r][0][3]);
            dv.y = (a[r][1][0] + a[r][1][1]) + (a[r][1][2] + a[r][1][3]);
            dv.z = (a[r][2][0] + a[r][2][1]) + (a[r][2][2] + a[r][2][3]);
            dv.w = (a[r][3][0] + a[r][3][1]) + (a[r][3][2] + a[r][3][3]);
            *(float4*)&D[(size_t)(rb + 64 * r + ln) * HID + o] = dv;
        }
    }
}

// ---------------------------------------------------------------------------
// Paired-LDS staging: WT2[j*PSTR + 2*l + h] = W[h*64+l][j]; row 128 = zeros.
// One ds_read_b64 yields (W^T[j][l], W^T[j][l+64]) for lane l.
// ---------------------------------------------------------------------------
__device__ __forceinline__ void stage_paired(float* __restrict__ WT2,
                                             const float* __restrict__ W,
                                             int tid, int nthreads)
{
    for (int i = tid; i < HID * HID / 4; i += nthreads) {
        int o = i >> 5, jq = i & 31;
        float4 v = ((const float4*)W)[i];
        int c = 2 * (o & 63) + (o >> 6);
        WT2[(4 * jq + 0) * PSTR + c] = v.x;
        WT2[(4 * jq + 1) * PSTR + c] = v.y;
        WT2[(4 * jq + 2) * PSTR + c] = v.z;
        WT2[(4 * jq + 3) * PSTR + c] = v.w;
    }
    for (int i = tid; i < PSTR; i += nthreads) WT2[128 * PSTR + i] = 0.f;
}

// Merged 128-bit extraction: next set bit ascending over (a then b);
// 128 = pad (zero LDS row, +0.0f exact identity). Wave-uniform scalar.
__device__ __forceinline__ int popnext(unsigned long long& a, unsigned long long& b)
{
    if (a) { int j = (int)__builtin_ctzll(a); a &= a - 1; return j; }
    if (b) { int j = 64 + (int)__builtin_ctzll(b); b &= b - 1; return j; }
    return 128;
}

// Sparse paired sum, 4-wide pops (used by spmm and remainder paths).
// Adds ascending into single accumulators — frozen bit-exact order.
__device__ __forceinline__ void sparse4p(const float* __restrict__ WT2,
                                         unsigned long long mm, int base,
                                         int ln2, float& rl, float& rh)
{
    while (mm) {
        int j0 = (int)__builtin_ctzll(mm) + base;            mm &= mm - 1;
        int j1 = mm ? (int)__builtin_ctzll(mm) + base : 128; mm &= mm - 1;
        int j2 = mm ? (int)__builtin_ctzll(mm) + base : 128; mm &= mm - 1;
        int j3 = mm ? (int)__builtin_ctzll(mm) + base : 128; mm &= mm - 1;
        float2 p0 = *(const float2*)&WT2[j0 * PSTR + ln2];
        float2 p1 = *(const float2*)&WT2[j1 * PSTR + ln2];
        float2 p2 = *(const float2*)&WT2[j2 * PSTR + ln2];
        float2 p3 = *(const float2*)&WT2[j3 * PSTR + ln2];
        rl += p0.x; rl += p1.x; rl += p2.x; rl += p3.x;
        rh += p0.y; rh += p1.y; rh += p2.y; rh += p3.y;
    }
}

// ---------------------------------------------------------------------------
// P1: layer-1 serial recurrence. ALL t-loop state in NAMED registers (round-4
// used dl[8]/dh[8] arrays -> scratch spill -> ~900cyc/step stall, VGPR=28).
// Per step: consume pre-issued rec loads, rare remainder, h, ballot, extract
// next indices + pre-issue loads, rotate depth-4 dense pipeline.
// ---------------------------------------------------------------------------
extern "C" __global__ void __launch_bounds__(128, 1)
srnn_recur1(const float* __restrict__ Dn, const float* __restrict__ Wh,
            const float* __restrict__ bi, const float* __restrict__ bh,
            ulonglong2* __restrict__ masks, ulonglong2* __restrict__ state,
            int t0, int Tc, int first)
{
    extern __shared__ float WT2[];     // [129][PSTR] paired, row 128 zeros
    const int tid = threadIdx.x, w = tid >> 6, ln = tid & 63, ln2 = 2 * ln;
    const int s = 2 * blockIdx.x + w;

    stage_paired(WT2, Wh, tid, 128);

    const float bil = bi[ln], bih = bi[64 + ln];
    const float bhl = bh[ln], bhh = bh[64 + ln];
    unsigned long long m0 = 0ULL, m1 = 0ULL;
    if (!first) { ulonglong2 st = state[s]; m0 = st.x; m1 = st.y; }
    __syncthreads();

    const float* Drow = Dn + (size_t)s * Tc * HID;
    // dense-term pipeline depth 4 — named scalars only
    const int i1 = 1 < Tc ? 1 : Tc - 1;
    const int i2 = 2 < Tc ? 2 : Tc - 1;
    const int i3 = 3 < Tc ? 3 : Tc - 1;
    float cl0 = Drow[ln],            ch0 = Drow[64 + ln];
    float cl1 = Drow[i1 * HID + ln], ch1 = Drow[i1 * HID + 64 + ln];
    float cl2 = Drow[i2 * HID + ln], ch2 = Drow[i2 * HID + 64 + ln];
    float cl3 = Drow[i3 * HID + ln], ch3 = Drow[i3 * HID + 64 + ln];

    // pre-issue rec loads for step 0
    unsigned long long a = m0, b = m1;
    int j0 = popnext(a, b), j1 = popnext(a, b), j2 = popnext(a, b), j3 = popnext(a, b);
    int j4 = popnext(a, b), j5 = popnext(a, b), j6 = popnext(a, b), j7 = popnext(a, b);
    float2 v0 = *(const float2*)&WT2[j0 * PSTR + ln2];
    float2 v1 = *(const float2*)&WT2[j1 * PSTR + ln2];
    float2 v2 = *(const float2*)&WT2[j2 * PSTR + ln2];
    float2 v3 = *(const float2*)&WT2[j3 * PSTR + ln2];
    float2 v4 = *(const float2*)&WT2[j4 * PSTR + ln2];
    float2 v5 = *(const float2*)&WT2[j5 * PSTR + ln2];
    float2 v6 = *(const float2*)&WT2[j6 * PSTR + ln2];
    float2 v7 = *(const float2*)&WT2[j7 * PSTR + ln2];
    unsigned long long ra = a, rb = b;

    #pragma unroll 4
    for (int t = 0; t < Tc; ++t) {
        // recurrent sum: slots ascending then remainder — frozen exact order
        float rl = 0.f, rh = 0.f;
        rl += v0.x; rl += v1.x; rl += v2.x; rl += v3.x;
        rl += v4.x; rl += v5.x; rl += v6.x; rl += v7.x;
        rh += v0.y; rh += v1.y; rh += v2.y; rh += v3.y;
        rh += v4.y; rh += v5.y; rh += v6.y; rh += v7.y;
        while (ra | rb) {                          // rare (>8 active bits)
            int k0 = popnext(ra, rb), k1 = popnext(ra, rb);
            int k2 = popnext(ra, rb), k3 = popnext(ra, rb);
            float2 q0 = *(const float2*)&WT2[k0 * PSTR + ln2];
            float2 q1 = *(const float2*)&WT2[k1 * PSTR + ln2];
            float2 q2 = *(const float2*)&WT2[k2 * PSTR + ln2];
            float2 q3 = *(const float2*)&WT2[k3 * PSTR + ln2];
            rl += q0.x; rl += q1.x; rl += q2.x; rl += q3.x;
            rh += q0.y; rh += q1.y; rh += q2.y; rh += q3.y;
        }

        float hl = ((cl0 + bil) + rl) + bhl;       // reference add order
        float hh = ((ch0 + bih) + rh) + bhh;
        m0 = __ballot(hl >= 1.0f);
        m1 = __ballot(hh >= 1.0f);
        if (ln == 0) {
            ulonglong2 mv; mv.x = m0; mv.y = m1;
            masks[(size_t)s * T_STEPS + (t0 + t)] = mv;
        }

        // extract + pre-issue next step's rec loads (overlaps LDS latency)
        a = m0; b = m1;
        j0 = popnext(a, b); j1 = popnext(a, b); j2 = popnext(a, b); j3 = popnext(a, b);
        j4 = popnext(a, b); j5 = popnext(a, b); j6 = popnext(a, b); j7 = popnext(a, b);
        v0 = *(const float2*)&WT2[j0 * PSTR + ln2];
        v1 = *(const float2*)&WT2[j1 * PSTR + ln2];
        v2 = *(const float2*)&WT2[j2 * PSTR + ln2];
        v3 = *(const float2*)&WT2[j3 * PSTR + ln2];
        v4 = *(const float2*)&WT2[j4 * PSTR + ln2];
        v5 = *(const float2*)&WT2[j5 * PSTR + ln2];
        v6 = *(const float2*)&WT2[j6 * PSTR + ln2];
        v7 = *(const float2*)&WT2[j7 * PSTR + ln2];
        ra = a; rb = b;

        // rotate dense pipeline, issue t+4
        cl0 = cl1; ch0 = ch1; cl1 = cl2; ch1 = ch2; cl2 = cl3; ch2 = ch3;
        int tn = (t + 4 < Tc) ? t + 4 : Tc - 1;
        cl3 = Drow[tn * HID + ln]; ch3 = Drow[tn * HID + 64 + ln];
    }
    if (ln == 0) { ulonglong2 st; st.x = m0; st.y = m1; state[s] = st; }
}

// ---------------------------------------------------------------------------
// P2: parallel sparse matmul D2[s,t,:] = s1(s,t)@Wi2^T. 32 rows/wave after
// one staging. Ascending single-accumulator order (frozen).
// ---------------------------------------------------------------------------
extern "C" __global__ void __launch_bounds__(256, 1)
srnn_spmm(const ulonglong2* __restrict__ masks1, const float* __restrict__ Wi2,
          float* __restrict__ D2, int t0, int Tc)
{
    extern __shared__ float WI2[];     // [129][PSTR] paired
    const int tid = threadIdx.x, w = tid >> 6, ln = tid & 63, ln2 = 2 * ln;
    stage_paired(WI2, Wi2, tid, 256);
    __syncthreads();

    const int s = blockIdx.y;
    const int tbase = (blockIdx.x * 4 + w) * SPMM_R;
    if (tbase >= Tc) return;
    const ulonglong2* mrow = masks1 + (size_t)s * T_STEPS + t0;

    ulonglong2 m = mrow[tbase];
    for (int r = 0; r < SPMM_R; ++r) {
        int trel = tbase + r;
        if (trel >= Tc) break;                     // wave-uniform
        ulonglong2 cm = m;
        if (r + 1 < SPMM_R && trel + 1 < Tc) m = mrow[trel + 1];

        float Al = 0.f, Ah = 0.f;
        sparse4p(WI2, cm.x, 0,  ln2, Al, Ah);
        sparse4p(WI2, cm.y, 64, ln2, Al, Ah);

        size_t ro = ((size_t)s * Tc + trel) * HID;
        D2[ro + ln] = Al;
        D2[ro + 64 + ln] = Ah;
    }
}

// ---------------------------------------------------------------------------
// P3: layer-2 serial recurrence + fused output accumulation. Same named-
// register pipeline as recur1; the per-step extracted indices serve BOTH the
// Wo dot (this step) and the Wh2 loads (next step).
// ---------------------------------------------------------------------------
extern "C" __global__ void __launch_bounds__(128, 1)
srnn_recur2(const float* __restrict__ D2, const float* __restrict__ Wh2,
            const float* __restrict__ bi2, const float* __restrict__ bh2,
            const float* __restrict__ Wo,  const float* __restrict__ bo,
            ulonglong2* __restrict__ state, float* __restrict__ accst,
            float* __restrict__ out, int t0, int Tc, int first, int last)
{
    extern __shared__ float sm2[];
    float* WT2 = sm2;                  // Wh2 paired [129][PSTR], row 128 zeros
    float* WOt = sm2 + 129 * PSTR;     // Wo^T [129][DOUT], row 128 zeros
    const int tid = threadIdx.x, w = tid >> 6, ln = tid & 63, ln2 = 2 * ln;
    const int s = 2 * blockIdx.x + w;

    stage_paired(WT2, Wh2, tid, 128);
    for (int i = tid; i < DOUT * HID / 4; i += 128) {
        int o = i >> 5, jq = i & 31;
        float4 v = ((const float4*)Wo)[i];
        WOt[(4 * jq + 0) * DOUT + o] = v.x; WOt[(4 * jq + 1) * DOUT + o] = v.y;
        WOt[(4 * jq + 2) * DOUT + o] = v.z; WOt[(4 * jq + 3) * DOUT + o] = v.w;
    }
    for (int i = tid; i < DOUT; i += 128) WOt[128 * DOUT + i] = 0.f;

    const float bil = bi2[ln], bih = bi2[64 + ln];
    const float bhl = bh2[ln], bhh = bh2[64 + ln];
    const bool  oth = (ln < DOUT);
    const int   c   = oth ? ln : 0;    // clamp for in-bounds LDS reads
    const float bov = oth ? bo[ln] : 0.f;
    unsigned long long p0 = 0ULL, p1 = 0ULL;
    float acc = 0.f;
    if (!first) {
        ulonglong2 st = state[s]; p0 = st.x; p1 = st.y;
        if (oth) acc = accst[s * DOUT + ln];
    }
    __syncthreads();

    const float* Drow = D2 + (size_t)s * Tc * HID;
    const int i1 = 1 < Tc ? 1 : Tc - 1;
    const int i2 = 2 < Tc ? 2 : Tc - 1;
    const int i3 = 3 < Tc ? 3 : Tc - 1;
    float cl0 = Drow[ln],            ch0 = Drow[64 + ln];
    float cl1 = Drow[i1 * HID + ln], ch1 = Drow[i1 * HID + 64 + ln];
    float cl2 = Drow[i2 * HID + ln], ch2 = Drow[i2 * HID + 64 + ln];
    float cl3 = Drow[i3 * HID + ln], ch3 = Drow[i3 * HID + 64 + ln];

    unsigned long long a = p0, b = p1;
    int j0 = popnext(a, b), j1 = popnext(a, b), j2 = popnext(a, b), j3 = popnext(a, b);
    int j4 = popnext(a, b), j5 = popnext(a, b), j6 = popnext(a, b), j7 = popnext(a, b);
    float2 v0 = *(const float2*)&WT2[j0 * PSTR + ln2];
    float2 v1 = *(const float2*)&WT2[j1 * PSTR + ln2];
    float2 v2 = *(const float2*)&WT2[j2 * PSTR + ln2];
    float2 v3 = *(const float2*)&WT2[j3 * PSTR + ln2];
    float2 v4 = *(const float2*)&WT2[j4 * PSTR + ln2];
    float2 v5 = *(const float2*)&WT2[j5 * PSTR + ln2];
    float2 v6 = *(const float2*)&WT2[j6 * PSTR + ln2];
    float2 v7 = *(const float2*)&WT2[j7 * PSTR + ln2];
    unsigned long long ra = a, rb = b;

    #pragma unroll 4
    for (int t = 0; t < Tc; ++t) {
        float Bl = 0.f, Bh = 0.f;
        Bl += v0.x; Bl += v1.x; Bl += v2.x; Bl += v3.x;
        Bl += v4.x; Bl += v5.x; Bl += v6.x; Bl += v7.x;
        Bh += v0.y; Bh += v1.y; Bh += v2.y; Bh += v3.y;
        Bh += v4.y; Bh += v5.y; Bh += v6.y; Bh += v7.y;
        while (ra | rb) {
            int k0 = popnext(ra, rb), k1 = popnext(ra, rb);
            int k2 = popnext(ra, rb), k3 = popnext(ra, rb);
            float2 q0 = *(const float2*)&WT2[k0 * PSTR + ln2];
            float2 q1 = *(const float2*)&WT2[k1 * PSTR + ln2];
            float2 q2 = *(const float2*)&WT2[k2 * PSTR + ln2];
            float2 q3 = *(const float2*)&WT2[k3 * PSTR + ln2];
            Bl += q0.x; Bl += q1.x; Bl += q2.x; Bl += q3.x;
            Bh += q0.y; Bh += q1.y; Bh += q2.y; Bh += q3.y;
        }

        float hl = ((cl0 + bil) + Bl) + bhl;       // reference add order
        float hh = ((ch0 + bih) + Bh) + bhh;
        p0 = __ballot(hl >= 1.0f);
        p1 = __ballot(hh >= 1.0f);

        // one extraction serves Wh2 (next step) and Wo (this step)
        a = p0; b = p1;
        j0 = popnext(a, b); j1 = popnext(a, b); j2 = popnext(a, b); j3 = popnext(a, b);
        j4 = popnext(a, b); j5 = popnext(a, b); j6 = popnext(a, b); j7 = popnext(a, b);
        v0 = *(const float2*)&WT2[j0 * PSTR + ln2];
        v1 = *(const float2*)&WT2[j1 * PSTR + ln2];
        v2 = *(const float2*)&WT2[j2 * PSTR + ln2];
        v3 = *(const float2*)&WT2[j3 * PSTR + ln2];
        v4 = *(const float2*)&WT2[j4 * PSTR + ln2];
        v5 = *(const float2*)&WT2[j5 * PSTR + ln2];
        v6 = *(const float2*)&WT2[j6 * PSTR + ln2];
        v7 = *(const float2*)&WT2[j7 * PSTR + ln2];
        float u0 = WOt[j0 * DOUT + c], u1 = WOt[j1 * DOUT + c];
        float u2 = WOt[j2 * DOUT + c], u3 = WOt[j3 * DOUT + c];
        float u4 = WOt[j4 * DOUT + c], u5 = WOt[j5 * DOUT + c];
        float u6 = WOt[j6 * DOUT + c], u7 = WOt[j7 * DOUT + c];
        unsigned long long oa = a, ob = b;         // Wo remainder (now)
        ra = a; rb = b;                            // rec remainder (next step)

        float d = 0.f;                             // frozen ascending order
        d += u0; d += u1; d += u2; d += u3; d += u4; d += u5; d += u6; d += u7;
        while (oa | ob) {
            int k0 = popnext(oa, ob), k1 = popnext(oa, ob);
            int k2 = popnext(oa, ob), k3 = popnext(oa, ob);
            float w0 = WOt[k0 * DOUT + c], w1 = WOt[k1 * DOUT + c];
            float w2 = WOt[k2 * DOUT + c], w3 = WOt[k3 * DOUT + c];
            d += w0; d += w1; d += w2; d += w3;
        }
        if (oth) { acc += d; acc += bov; }         // (acc + dot) + bo

        cl0 = cl1; ch0 = ch1; cl1 = cl2; ch1 = ch2; cl2 = cl3; ch2 = ch3;
        int tn = (t + 4 < Tc) ? t + 4 : Tc - 1;
        cl3 = Drow[tn * HID + ln]; ch3 = Drow[tn * HID + 64 + ln];
    }
    if (ln == 0) { ulonglong2 st; st.x = p0; st.y = p1; state[s] = st; }
    if (oth) {
        if (last) out[s * DOUT + ln] = acc / (float)T_STEPS;
        else      accst[s * DOUT + ln] = acc;
    }
}

// ---------------------------------------------------------------------------
extern "C" void kernel_launch(void* const* d_in, const int* in_sizes, int n_in,
                              void* d_out, int out_size, void* d_ws, size_t ws_size,
                              hipStream_t stream) {
    const float* x   = (const float*)d_in[0];
    const float* Wi1 = (const float*)d_in[1];
    const float* bi1 = (const float*)d_in[2];
    const float* Wh1 = (const float*)d_in[3];
    const float* bh1 = (const float*)d_in[4];
    const float* Wi2 = (const float*)d_in[5];
    const float* bi2 = (const float*)d_in[6];
    const float* Wh2 = (const float*)d_in[7];
    const float* bh2 = (const float*)d_in[8];
    const float* Wo  = (const float*)d_in[9];
    const float* bo  = (const float*)d_in[10];
    float* out = (float*)d_out;

    // ws: [masks1 8.19M][state 16K][accst 40K][D / D2 shared chunk buffer]
    const size_t mb = (size_t)NS * T_STEPS * sizeof(ulonglong2);
    ulonglong2* masks1 = (ulonglong2*)d_ws;
    ulonglong2* state  = (ulonglong2*)((char*)d_ws + mb);
    const size_t state_bytes = (size_t)2 * NS * sizeof(ulonglong2);
    float* accst = (float*)((char*)d_ws + mb + state_bytes);
    const size_t acc_bytes = (size_t)NS * DOUT * sizeof(float);
    float* Dbuf = (float*)((char*)d_ws + mb + state_bytes + acc_bytes);

    const size_t base = mb + state_bytes + acc_bytes;
    size_t avail = ws_size > base ? ws_size - base : 0;
    const size_t bytes_per_t = (size_t)NS * HID * sizeof(float);  // 256 KB
    long tcmax = (long)(avail / bytes_per_t);
    // divisors of 1000 that are multiples of 4 (clean unroll-4 t-loops)
    static const int divs[] = {1000, 500, 200, 100, 40, 20, 8, 4};
    int Tc = 4;
    for (int i = 0; i < 8; ++i) if (divs[i] <= tcmax) { Tc = divs[i]; break; }

    const int lds0 = (128 * XPAD + HID * HID) * (int)sizeof(float);
    const int ldsP = (129 * PSTR) * (int)sizeof(float);
    const int lds2 = (129 * PSTR + 129 * DOUT) * (int)sizeof(float);
    hipFuncSetAttribute((const void*)srnn_dense,
                        hipFuncAttributeMaxDynamicSharedMemorySize, lds0);
    hipFuncSetAttribute((const void*)srnn_recur1,
                        hipFuncAttributeMaxDynamicSharedMemorySize, ldsP);
    hipFuncSetAttribute((const void*)srnn_spmm,
                        hipFuncAttributeMaxDynamicSharedMemorySize, ldsP);
    hipFuncSetAttribute((const void*)srnn_recur2,
                        hipFuncAttributeMaxDynamicSharedMemorySize, lds2);

    // Phase A: layer-1 (dense GEMM chunk -> serial recurrence chunk)
    for (int t0 = 0; t0 < T_STEPS; t0 += Tc) {
        srnn_dense<<<4 * Tc, 512, lds0, stream>>>(x, Wi1, Dbuf, t0, Tc);
        srnn_recur1<<<NS / 2, 128, ldsP, stream>>>(Dbuf, Wh1, bi1, bh1,
                                                   masks1, state, t0, Tc, t0 == 0);
    }
    // Phase B: layer-2 (parallel spmm chunk -> serial recurrence + output)
    for (int t0 = 0; t0 < T_STEPS; t0 += Tc) {
        dim3 g2((Tc + 4 * SPMM_R - 1) / (4 * SPMM_R), NS);
        srnn_spmm<<<g2, 256, ldsP, stream>>>(masks1, Wi2, Dbuf, t0, Tc);
        srnn_recur2<<<NS / 2, 128, lds2, stream>>>(Dbuf, Wh2, bi2, bh2, Wo, bo,
                                                   state + NS, accst, out,
                                                   t0, Tc, t0 == 0,
                                                   t0 + Tc >= T_STEPS);
    }
}